// Round 12
// baseline (1758.996 us; speedup 1.0000x reference)
//
#include <hip/hip_runtime.h>
#include <hip/hip_bf16.h>
#include <cstdint>

#define BB 4
#define C_IN 512
#define HH 64
#define WW 64
#define HWN 4096
#define QKV_CH 1536
#define NHEADS2 128
#define TD2 1024
#define EPS_F 1e-5f
#define BN_EPS_F 1e-5f

// Row map: part-local row m (0..511) -> original w_qkv row (head*24 + p*8 + d)
__device__ __forceinline__ int amap(int m, int p) {
    return (m >> 3) * 24 + p * 8 + (m & 7);
}

// ---------------- K1q: Q = w_qkv[q-rows] * x, fp32 I/O, f64 accumulate -------
// R4-proven inner loop (f32 LDS, inline converts, K-step 8). M=512.
__global__ __launch_bounds__(256) void gemm_q_f64(
    const float* __restrict__ A, const float* __restrict__ Bm,
    float* __restrict__ Cm, int N, int K)
{
    __shared__ float As[8][64];
    __shared__ float Bs[8][128];
    const float* Bp = Bm;
    float*       Cp = Cm;
    const int m0 = blockIdx.y * 64;
    const int n0 = blockIdx.x * 128;
    const int tid = threadIdx.x;
    const int tx = tid & 15;   // n sub-tile (8 cols)
    const int ty = tid >> 4;   // m sub-tile (4 rows)

    const int a_row = tid >> 1;          // 0..63 for tid<128
    const int a_col = (tid & 1) << 2;
    const int b_row = tid >> 5;          // 0..7
    const int b_col = (tid & 31) << 2;   // 0..124

    const float* Aptr = A + (size_t)amap(m0 + a_row, 0) * K + a_col;
    const float* Bptr = Bp + (size_t)b_row * N + n0 + b_col;

    float4 av = make_float4(0.f, 0.f, 0.f, 0.f);
    if (tid < 128) av = *reinterpret_cast<const float4*>(Aptr);
    float4 bv = *reinterpret_cast<const float4*>(Bptr);

    double acc[4][8];
#pragma unroll
    for (int i = 0; i < 4; ++i)
#pragma unroll
        for (int j = 0; j < 8; ++j) acc[i][j] = 0.0;

    for (int k0 = 0; k0 < K; k0 += 8) {
        if (tid < 128) {
            As[a_col + 0][a_row] = av.x;
            As[a_col + 1][a_row] = av.y;
            As[a_col + 2][a_row] = av.z;
            As[a_col + 3][a_row] = av.w;
        }
        *reinterpret_cast<float4*>(&Bs[b_row][b_col]) = bv;
        __syncthreads();
        if (k0 + 8 < K) {
            if (tid < 128) av = *reinterpret_cast<const float4*>(Aptr + k0 + 8);
            bv = *reinterpret_cast<const float4*>(Bptr + (size_t)(k0 + 8) * N);
        }
#pragma unroll
        for (int kk = 0; kk < 8; ++kk) {
            float am[4], bn[8];
            *reinterpret_cast<float4*>(&am[0]) = *reinterpret_cast<const float4*>(&As[kk][ty * 4]);
            *reinterpret_cast<float4*>(&bn[0]) = *reinterpret_cast<const float4*>(&Bs[kk][tx * 8]);
            *reinterpret_cast<float4*>(&bn[4]) = *reinterpret_cast<const float4*>(&Bs[kk][tx * 8 + 4]);
#pragma unroll
            for (int i = 0; i < 4; ++i) {
                const double ad = (double)am[i];
#pragma unroll
                for (int j = 0; j < 8; ++j)
                    acc[i][j] = fma(ad, (double)bn[j], acc[i][j]);
            }
        }
        __syncthreads();
    }

#pragma unroll
    for (int i = 0; i < 4; ++i) {
        float* cp = Cp + (size_t)(m0 + ty * 4 + i) * N + n0 + tx * 8;
        float4 o0, o1;
        o0.x = (float)acc[i][0]; o0.y = (float)acc[i][1];
        o0.z = (float)acc[i][2]; o0.w = (float)acc[i][3];
        o1.x = (float)acc[i][4]; o1.y = (float)acc[i][5];
        o1.z = (float)acc[i][6]; o1.w = (float)acc[i][7];
        *reinterpret_cast<float4*>(cp) = o0;
        *reinterpret_cast<float4*>(cp + 4) = o1;
    }
}

// ---------------- K1k/K1v: part GEMM fp32 (128x128 tile), M=512 --------------
// k,v enter the attention LINEARLY (no relu-sign amplification: d(out)/d(kv)
// <= 1/ksum ~ 6e-4, f32 noise ~1e-6 -> ~1e-9 on y). f32 is safe.
__global__ __launch_bounds__(256) void gemm_kv_f32(
    const float* __restrict__ A, const float* __restrict__ Bm,
    float* __restrict__ Cm, int N, int K, int p)
{
    __shared__ float As[8][128];
    __shared__ float Bs[8][128];
    const float* Bp = Bm;
    float*       Cp = Cm;
    const int m0 = blockIdx.y * 128;
    const int n0 = blockIdx.x * 128;
    const int tid = threadIdx.x;
    const int tx = tid & 15;
    const int ty = tid >> 4;

    const int a_row = tid >> 1;          // 0..127
    const int a_col = (tid & 1) << 2;
    const int b_row = tid >> 5;
    const int b_col = (tid & 31) << 2;

    const float* Aptr = A + (size_t)amap(m0 + a_row, p) * K + a_col;
    const float* Bptr = Bp + (size_t)b_row * N + n0 + b_col;

    float4 av = *reinterpret_cast<const float4*>(Aptr);
    float4 bv = *reinterpret_cast<const float4*>(Bptr);

    float acc[8][8];
#pragma unroll
    for (int i = 0; i < 8; ++i)
#pragma unroll
        for (int j = 0; j < 8; ++j) acc[i][j] = 0.f;

    for (int k0 = 0; k0 < K; k0 += 8) {
        As[a_col + 0][a_row] = av.x;
        As[a_col + 1][a_row] = av.y;
        As[a_col + 2][a_row] = av.z;
        As[a_col + 3][a_row] = av.w;
        *reinterpret_cast<float4*>(&Bs[b_row][b_col]) = bv;
        __syncthreads();
        if (k0 + 8 < K) {
            av = *reinterpret_cast<const float4*>(Aptr + k0 + 8);
            bv = *reinterpret_cast<const float4*>(Bptr + (size_t)(k0 + 8) * N);
        }
#pragma unroll
        for (int kk = 0; kk < 8; ++kk) {
            float am[8], bn[8];
            *reinterpret_cast<float4*>(&am[0]) = *reinterpret_cast<const float4*>(&As[kk][ty * 8]);
            *reinterpret_cast<float4*>(&am[4]) = *reinterpret_cast<const float4*>(&As[kk][ty * 8 + 4]);
            *reinterpret_cast<float4*>(&bn[0]) = *reinterpret_cast<const float4*>(&Bs[kk][tx * 8]);
            *reinterpret_cast<float4*>(&bn[4]) = *reinterpret_cast<const float4*>(&Bs[kk][tx * 8 + 4]);
#pragma unroll
            for (int i = 0; i < 8; ++i)
#pragma unroll
                for (int j = 0; j < 8; ++j)
                    acc[i][j] = fmaf(am[i], bn[j], acc[i][j]);
        }
        __syncthreads();
    }

#pragma unroll
    for (int i = 0; i < 8; ++i) {
        float* cp = Cp + (size_t)(m0 + ty * 8 + i) * N + n0 + tx * 8;
        float4 o0, o1;
        o0.x = acc[i][0]; o0.y = acc[i][1]; o0.z = acc[i][2]; o0.w = acc[i][3];
        o1.x = acc[i][4]; o1.y = acc[i][5]; o1.z = acc[i][6]; o1.w = acc[i][7];
        *reinterpret_cast<float4*>(cp) = o0;
        *reinterpret_cast<float4*>(cp + 4) = o1;
    }
}

// ---------------- K5: tiled fp32 GEMM with split-K-source B + BN epilogue ----
__global__ __launch_bounds__(256) void gemm_f32_epi(
    const float* __restrict__ A,
    const float* __restrict__ B0, const float* __restrict__ B1, int KR0,
    float* __restrict__ Cm, int M, int N, int K,
    const float* __restrict__ g_gamma, const float* __restrict__ g_beta,
    const float* __restrict__ g_mean, const float* __restrict__ g_var)
{
    __shared__ float As[8][128];
    __shared__ float Bs[8][128];
    const float* B0p = B0;
    const float* B1p = B1 - (size_t)KR0 * N;   // so (B1p + row*N) valid for row>=KR0
    float* Cp = Cm;
    const int m0 = blockIdx.y * 128;
    const int n0 = blockIdx.x * 128;
    const int tid = threadIdx.x;
    const int tx = tid & 15;
    const int ty = tid >> 4;

    const int a_row = tid >> 1;
    const int a_col = (tid & 1) << 2;
    const int b_row = tid >> 5;
    const int b_col = (tid & 31) << 2;

    const float* Aptr = A + (size_t)(m0 + a_row) * K + a_col;

    auto loadB = [&](int row) -> float4 {
        const float* base = (row < KR0) ? B0p : B1p;
        return *reinterpret_cast<const float4*>(base + (size_t)row * N + n0 + b_col);
    };

    float4 av = *reinterpret_cast<const float4*>(Aptr);
    float4 bv = loadB(b_row);

    float acc[8][8];
#pragma unroll
    for (int i = 0; i < 8; ++i)
#pragma unroll
        for (int j = 0; j < 8; ++j) acc[i][j] = 0.f;

    for (int k0 = 0; k0 < K; k0 += 8) {
        As[a_col + 0][a_row] = av.x;
        As[a_col + 1][a_row] = av.y;
        As[a_col + 2][a_row] = av.z;
        As[a_col + 3][a_row] = av.w;
        *reinterpret_cast<float4*>(&Bs[b_row][b_col]) = bv;
        __syncthreads();
        if (k0 + 8 < K) {
            av = *reinterpret_cast<const float4*>(Aptr + k0 + 8);
            bv = loadB(k0 + 8 + b_row);
        }
#pragma unroll
        for (int kk = 0; kk < 8; ++kk) {
            float am[8], bn[8];
            *reinterpret_cast<float4*>(&am[0]) = *reinterpret_cast<const float4*>(&As[kk][ty * 8]);
            *reinterpret_cast<float4*>(&am[4]) = *reinterpret_cast<const float4*>(&As[kk][ty * 8 + 4]);
            *reinterpret_cast<float4*>(&bn[0]) = *reinterpret_cast<const float4*>(&Bs[kk][tx * 8]);
            *reinterpret_cast<float4*>(&bn[4]) = *reinterpret_cast<const float4*>(&Bs[kk][tx * 8 + 4]);
#pragma unroll
            for (int i = 0; i < 8; ++i)
#pragma unroll
                for (int j = 0; j < 8; ++j)
                    acc[i][j] = fmaf(am[i], bn[j], acc[i][j]);
        }
        __syncthreads();
    }

#pragma unroll
    for (int i = 0; i < 8; ++i) {
        const int row = m0 + ty * 8 + i;
        const float sc = g_gamma[row] * rsqrtf(g_var[row] + BN_EPS_F);
        const float ad = g_beta[row] - g_mean[row] * sc;
        float* cp = Cp + (size_t)row * N + n0 + tx * 8;
        float4 o0, o1;
        o0.x = acc[i][0] * sc + ad; o0.y = acc[i][1] * sc + ad;
        o0.z = acc[i][2] * sc + ad; o0.w = acc[i][3] * sc + ad;
        o1.x = acc[i][4] * sc + ad; o1.y = acc[i][5] * sc + ad;
        o1.z = acc[i][6] * sc + ad; o1.w = acc[i][7] * sc + ad;
        *reinterpret_cast<float4*>(cp) = o0;
        *reinterpret_cast<float4*>(cp + 4) = o1;
    }
}

// ---------------- K2: per-part fused dw 5x5 conv + 8x8 pointwise -------------
// src/dst: part buffers [512][HW], row = head*8 + ch. Group g = 3*head+p.
// ACC=double for the q part (relu-sign critical), float for k,v.
template <typename ACC>
__global__ __launch_bounds__(256) void dw_pw_part(
    const float* __restrict__ src, const float* __restrict__ w_dw,
    const float* __restrict__ w_pw, float* __restrict__ dst, int p)
{
    __shared__ float s_in[8][36][36];
    __shared__ float s_wd[200];
    __shared__ float s_wp[64];
    const int h = blockIdx.y;   // head 0..63
    const int g = 3 * h + p;
    const int ty0 = (blockIdx.x >> 1) * 32;
    const int tx0 = (blockIdx.x & 1) * 32;
    const int tid = threadIdx.x;

    for (int idx = tid; idx < 8 * 36 * 36; idx += 256) {
        const int i = idx / 1296;
        const int r = idx - i * 1296;
        const int yy = r / 36;
        const int xx = r - yy * 36;
        const int gy = ty0 + yy - 2, gx = tx0 + xx - 2;
        float v = 0.f;
        if (gy >= 0 && gy < HH && gx >= 0 && gx < WW)
            v = src[((size_t)h * 8 + i) * HWN + gy * WW + gx];
        s_in[i][yy][xx] = v;
    }
    if (tid < 200) s_wd[tid] = w_dw[(size_t)g * 200 + tid];
    if (tid >= 200 && tid < 264) s_wp[tid - 200] = w_pw[(size_t)g * 64 + tid - 200];
    __syncthreads();

    const int py = tid >> 3;        // 0..31
    const int xq = (tid & 7) << 2;  // 0..28 step 4

    ACC outp[8][4];
#pragma unroll
    for (int o = 0; o < 8; ++o)
#pragma unroll
        for (int pp = 0; pp < 4; ++pp) outp[o][pp] = (ACC)0;

#pragma unroll
    for (int i = 0; i < 8; ++i) {
        ACC dw4[4] = {(ACC)0, (ACC)0, (ACC)0, (ACC)0};
#pragma unroll
        for (int dy = 0; dy < 5; ++dy) {
            const float* row = &s_in[i][py + dy][xq];
            float rr[8];
            *reinterpret_cast<float4*>(&rr[0]) = *reinterpret_cast<const float4*>(&row[0]);
            *reinterpret_cast<float4*>(&rr[4]) = *reinterpret_cast<const float4*>(&row[4]);
#pragma unroll
            for (int dx = 0; dx < 5; ++dx) {
                const ACC w = (ACC)s_wd[i * 25 + dy * 5 + dx];
#pragma unroll
                for (int pp = 0; pp < 4; ++pp)
                    dw4[pp] += (ACC)rr[pp + dx] * w;
            }
        }
#pragma unroll
        for (int o = 0; o < 8; ++o) {
            const ACC w = (ACC)s_wp[o * 8 + i];
#pragma unroll
            for (int pp = 0; pp < 4; ++pp) outp[o][pp] += dw4[pp] * w;
        }
    }
#pragma unroll
    for (int o = 0; o < 8; ++o) {
        float4 ov;
        ov.x = (float)outp[o][0]; ov.y = (float)outp[o][1];
        ov.z = (float)outp[o][2]; ov.w = (float)outp[o][3];
        *reinterpret_cast<float4*>(
            &dst[((size_t)h * 8 + o) * HWN + (ty0 + py) * WW + tx0 + xq]) = ov;
    }
}

// ---------------- K3: kv[h,d,e] = sum_n relu(k)*[v,1] -------------------------
__global__ __launch_bounds__(256) void kv_reduce(
    const float* __restrict__ Ka, const float* __restrict__ Kb,
    const float* __restrict__ Va, const float* __restrict__ Vb,
    float* __restrict__ kv)
{
    const int h = blockIdx.x;  // 0..127
    const size_t off = (size_t)(h & 63) * 8 * HWN;
    const float* sk = (h < 64 ? Ka : Kb) + off;
    const float* sv = (h < 64 ? Va : Vb) + off;
    const int tid = threadIdx.x;

    float acc[72];
#pragma unroll
    for (int j = 0; j < 72; ++j) acc[j] = 0.f;

    for (int n = tid; n < HWN; n += 256) {
        float kk[8], vv[8];
#pragma unroll
        for (int d = 0; d < 8; ++d) kk[d] = fmaxf(sk[(size_t)d * HWN + n], 0.f);
#pragma unroll
        for (int e = 0; e < 8; ++e) vv[e] = sv[(size_t)e * HWN + n];
#pragma unroll
        for (int d = 0; d < 8; ++d) {
#pragma unroll
            for (int e = 0; e < 8; ++e) acc[d * 9 + e] = fmaf(kk[d], vv[e], acc[d * 9 + e]);
            acc[d * 9 + 8] += kk[d];
        }
    }

    __shared__ float red[4][72];
    const int lane = tid & 63, wid = tid >> 6;
#pragma unroll
    for (int j = 0; j < 72; ++j) {
        float v = acc[j];
#pragma unroll
        for (int off2 = 32; off2 >= 1; off2 >>= 1) v += __shfl_xor(v, off2);
        if (lane == 0) red[wid][j] = v;
    }
    __syncthreads();
    if (tid < 72) {
        const float s = red[0][tid] + red[1][tid] + red[2][tid] + red[3][tid];
        kv[(size_t)h * 72 + tid] = s;
    }
}

// ---------------- K4: out = (relu(q)·kv)[:8] / ((relu(q)·kv)[8]+eps) ---------
__global__ __launch_bounds__(256) void attn_out(
    const float* __restrict__ Qbuf, const float* __restrict__ kv,
    float* __restrict__ dst, int h_off)
{
    const int hl = blockIdx.x;  // 0..63
    const float* src = Qbuf + (size_t)hl * 8 * HWN;
    __shared__ float skv[72];
    if (threadIdx.x < 72)
        skv[threadIdx.x] = kv[(size_t)(h_off + hl) * 72 + threadIdx.x];
    __syncthreads();
    float* dstp = dst + (size_t)hl * 8 * HWN;

    for (int n = threadIdx.x; n < HWN; n += 256) {
        float q[8];
#pragma unroll
        for (int d = 0; d < 8; ++d) q[d] = fmaxf(src[(size_t)d * HWN + n], 0.f);
        float num[9];
#pragma unroll
        for (int e = 0; e < 9; ++e) {
            float s = 0.f;
#pragma unroll
            for (int d = 0; d < 8; ++d) s = fmaf(q[d], skv[d * 9 + e], s);
            num[e] = s;
        }
        const float r = 1.f / (num[8] + EPS_F);
#pragma unroll
        for (int e = 0; e < 8; ++e) dstp[(size_t)e * HWN + n] = num[e] * r;
    }
}

// ------------------------------------------------------------------------------
extern "C" void kernel_launch(void* const* d_in, const int* in_sizes, int n_in,
                              void* d_out, int out_size, void* d_ws, size_t ws_size,
                              hipStream_t stream)
{
    const float* x      = (const float*)d_in[0];
    const float* w_qkv  = (const float*)d_in[1];
    const float* w_dw   = (const float*)d_in[2];
    const float* w_pw   = (const float*)d_in[3];
    const float* w_proj = (const float*)d_in[4];
    const float* gamma  = (const float*)d_in[5];
    const float* beta   = (const float*)d_in[6];
    const float* mean   = (const float*)d_in[7];
    const float* var    = (const float*)d_in[8];
    float* out = (float*)d_out;

    // Per-batch part buffers [512][HW] f32 = 8.39 MB each.
    // kv(9216) + 6 parts + out_tA = 58.8 MB (ws-safe).
    const size_t PSZ = (size_t)512 * HWN;
    float* kv     = (float*)d_ws;               // 128*72
    float* Qa     = kv + (size_t)NHEADS2 * 72;
    float* Ka     = Qa + PSZ;
    float* Va     = Ka + PSZ;
    float* Qb     = Va + PSZ;
    float* Kb     = Qb + PSZ;
    float* Vb     = Kb + PSZ;
    float* out_tA = Vb + PSZ;                   // heads 0..63 attn out
    float* out_tB = Qa;                         // alias: Qa dead after K4a

    for (int b = 0; b < BB; ++b) {
        const float* xb   = x + (size_t)b * C_IN * HWN;
        float*       outb = out + (size_t)b * C_IN * HWN;

        // K1: per-part GEMMs. Only q needs f64 (eps-division amplifies
        // near-zero q sign errors); k,v enter linearly -> f32.
        gemm_q_f64<<<dim3(HWN / 128, 8, 1), 256, 0, stream>>>(
            w_qkv, xb, Qa, HWN, C_IN);
        gemm_kv_f32<<<dim3(HWN / 128, 4, 1), 256, 0, stream>>>(
            w_qkv, xb, Ka, HWN, C_IN, 1);
        gemm_kv_f32<<<dim3(HWN / 128, 4, 1), 256, 0, stream>>>(
            w_qkv, xb, Va, HWN, C_IN, 2);

        // K2: fused dw conv + pointwise, per part. Only q part in f64.
        dw_pw_part<double><<<dim3(4, 64, 1), 256, 0, stream>>>(Qa, w_dw, w_pw, Qb, 0);
        dw_pw_part<float ><<<dim3(4, 64, 1), 256, 0, stream>>>(Ka, w_dw, w_pw, Kb, 1);
        dw_pw_part<float ><<<dim3(4, 64, 1), 256, 0, stream>>>(Va, w_dw, w_pw, Vb, 2);

        // K3: kv reduction
        kv_reduce<<<dim3(NHEADS2, 1), 256, 0, stream>>>(Ka, Kb, Va, Vb, kv);

        // K4a: heads 0..63 (Qa) -> out_tA.  K4b: heads 64..127 (Qb) -> out_tB
        // (aliases Qa; Qa dead once K4a completes; stream-ordered).
        attn_out<<<dim3(64, 1), 256, 0, stream>>>(Qa, kv, out_tA, 0);
        attn_out<<<dim3(64, 1), 256, 0, stream>>>(Qb, kv, out_tB, 64);

        // K5: y_b = w_proj (512x1024) * [out_tA; out_tB] + BN affine
        gemm_f32_epi<<<dim3(HWN / 128, C_IN / 128, 1), 256, 0, stream>>>(
            w_proj, out_tA, out_tB, 512, outb, C_IN, HWN, TD2,
            gamma, beta, mean, var);
    }
}